// Round 13
// baseline (962.695 us; speedup 1.0000x reference)
//
#include <hip/hip_runtime.h>

#define S_ 32
#define O_ 64
#define T_ 91
#define C_ 128
#define H_ 8
#define HD_ 16

typedef __attribute__((ext_vector_type(8))) short short8;
typedef __attribute__((ext_vector_type(4))) short short4b;
typedef __attribute__((ext_vector_type(4))) float f32x4;

// Pre-split weights (bf16 hi/lo, MFMA-frag-linear), written by prep_all each call.
__device__ short g_wqa_h[384 * 128], g_wqa_l[384 * 128];
__device__ short g_wqt_h[384 * 128], g_wqt_l[384 * 128];
__device__ short g_wpa_h[128 * 128], g_wpa_l[128 * 128];
__device__ short g_wpt_h[128 * 128], g_wpt_l[128 * 128];

__device__ __forceinline__ void splitf(float f, short& h, short& l) {
    unsigned u = __float_as_uint(f);
    float hf = __uint_as_float(u & 0xffff0000u);
    h = (short)(u >> 16);
    l = (short)(__float_as_uint(f - hf) >> 16);
}

__device__ __forceinline__ void split8g(const float* p, short8& h, short8& l) {
    float4 a = *(const float4*)p;
    float4 b = *(const float4*)(p + 4);
    float v[8] = {a.x, a.y, a.z, a.w, b.x, b.y, b.z, b.w};
    #pragma unroll
    for (int j = 0; j < 8; ++j) { short hh, ll; splitf(v[j], hh, ll); h[j] = hh; l[j] = ll; }
}

__device__ __forceinline__ void split4v(f32x4 v, short4b& h, short4b& l) {
    #pragma unroll
    for (int j = 0; j < 4; ++j) { short hh, ll; splitf(v[j], hh, ll); h[j] = hh; l[j] = ll; }
}

// ---------------------------------------------------------------------------
// Weight prep: all four matrices -> hi/lo bf16, frag-linear:
// element (c,k): ct=c>>4, cl=c&15, kp=k>>5, gg=(k>>3)&3, j=k&7
//   slot = ct*2048 + kp*512 + (cl+16*gg)*8 + j
// ---------------------------------------------------------------------------
__global__ __launch_bounds__(256) void prep_all(
    const float* __restrict__ wqa, const float* __restrict__ wqt,
    const float* __restrict__ wpa, const float* __restrict__ wpt)
{
    int t = blockIdx.x * 256 + threadIdx.x;     // 16384 total
    const float* src; short* dh; short* dl; int idx;
    if (t < 6144)       { src = wqa; dh = g_wqa_h; dl = g_wqa_l; idx = t; }
    else if (t < 12288) { src = wqt; dh = g_wqt_h; dl = g_wqt_l; idx = t - 6144; }
    else if (t < 14336) { src = wpa; dh = g_wpa_h; dl = g_wpa_l; idx = t - 12288; }
    else                { src = wpt; dh = g_wpt_h; dl = g_wpt_l; idx = t - 14336; }
    int c = idx >> 4, gk = idx & 15;
    int kp = gk >> 2, gg = gk & 3;
    int ct = c >> 4, cl = c & 15;
    const float* s = src + (long)c * C_ + gk * 8;
    long slot = (long)ct * 2048 + kp * 512 + (cl + 16 * gg) * 8;
    short8 vh, vl;
    split8g(s, vh, vl);
    *(short8*)(dh + slot) = vh;
    *(short8*)(dl + slot) = vl;
}

// ---------------------------------------------------------------------------
// K1: QKV + masked attention. Block = one batch, 4 waves, 2 heads/wave
// (non-unrolled hp loop). KEY-HALF STREAMING (round-12 lesson: holding all
// Q,K,V frags spills): only NT/2 K/V tiles live at a time; unnormalized
// pvacc[it] + sum[it] accumulate across halves (softmax has no max-sub, so
// key order is free); single normalization at the end. Peak regs ~100.
// y written to ws as plain f32 row-major.
// ---------------------------------------------------------------------------
template<int N, int NT, int PASS>
__global__ __launch_bounds__(256, 3) void attn_pass(
    const float* __restrict__ xg, const int* __restrict__ mask,
    float* __restrict__ yws,
    int bdiv, long bs1, long bs2, long ts, long m1, long m2)
{
    constexpr bool FULL = (NT * 16 == N);
    constexpr int NH = NT / 2;                      // key tiles per half
    extern __shared__ char smem[];
    short* xh = (short*)smem;                       // NT*2048 shorts
    short* xl = xh + NT * 2048;                     // NT*2048 shorts
    int*   s_m = (int*)(smem + NT * 8192);          // NT*16 ints

    const short* Wh = (PASS == 0) ? g_wqa_h : g_wqt_h;
    const short* Wl = (PASS == 0) ? g_wqa_l : g_wqt_l;

    const int tid = threadIdx.x;
    const int wv = tid >> 6, l = tid & 63;
    const int ic = l & 15, g = l >> 4;
    const int b = blockIdx.x;
    const int s = b / bdiv, u = b - s * bdiv;
    const long xbase = (long)s * bs1 + (long)u * bs2;
    const long mbase = (long)s * (O_ * T_) + (long)u * m1;

    // ---- Stage 0: stage x (split, frag-linear) + mask
    for (int gi = tid; gi < NT * 256; gi += 256) {
        int token = gi >> 4, cg = gi & 15;
        int kp = cg >> 2, gg = cg & 3;
        int slot = ((token >> 4) * 4 + kp) * 512 + (gg * 16 + (token & 15)) * 8;
        short8 vh, vl;
        if (FULL || token < N) {
            split8g(xg + xbase + (long)token * ts + cg * 8, vh, vl);
        } else {
            #pragma unroll
            for (int j = 0; j < 8; ++j) { vh[j] = 0; vl[j] = 0; }
        }
        *(short8*)(xh + slot) = vh;
        *(short8*)(xl + slot) = vl;
    }
    for (int idx = tid; idx < NT * 16; idx += 256)
        s_m[idx] = (idx < N) ? (mask[mbase + (long)idx * m2] != 0) : 0;
    __syncthreads();

    // per-lane key bitmasks: key j = jt*16 + 4g + r -> bit jt*4+r
    unsigned jbits = 0, mbits = 0;
    #pragma unroll
    for (int jt = 0; jt < NT; ++jt)
        #pragma unroll
        for (int r = 0; r < 4; ++r) {
            int j = jt * 16 + 4 * g + r;
            if (j < N) {
                jbits |= 1u << (jt * 4 + r);
                if (s_m[j]) mbits |= 1u << (jt * 4 + r);
            }
        }

    const float QS = 0.25f * 1.44269504088896f;   // softmax scale * log2(e), folded into Q

    #pragma unroll 1
    for (int hp = 0; hp < 2; ++hp) {
        const int h = wv + hp * 4;

        // ---- Q frags (all tiles); aQ retired before anything else goes live
        short4b qfh[NT], qfl[NT];
        {
            f32x4 aQ[NT];
            #pragma unroll
            for (int t2 = 0; t2 < NT; ++t2) aQ[t2] = (f32x4){0.f,0.f,0.f,0.f};
            #pragma unroll
            for (int kp = 0; kp < 4; ++kp) {
                short8 wqh = *(const short8*)(Wh + (h * 4 + kp) * 512 + l * 8);
                short8 wql = *(const short8*)(Wl + (h * 4 + kp) * 512 + l * 8);
                #pragma unroll
                for (int tt = 0; tt < NT; ++tt) {
                    short8 xhv = *(const short8*)(xh + (tt * 4 + kp) * 512 + l * 8);
                    short8 xlv = *(const short8*)(xl + (tt * 4 + kp) * 512 + l * 8);
                    aQ[tt] = __builtin_amdgcn_mfma_f32_16x16x32_bf16(wqh, xhv, aQ[tt], 0, 0, 0);
                    aQ[tt] = __builtin_amdgcn_mfma_f32_16x16x32_bf16(wql, xhv, aQ[tt], 0, 0, 0);
                    aQ[tt] = __builtin_amdgcn_mfma_f32_16x16x32_bf16(wqh, xlv, aQ[tt], 0, 0, 0);
                }
            }
            #pragma unroll
            for (int t2 = 0; t2 < NT; ++t2) {
                f32x4 qs = aQ[t2] * QS;
                split4v(qs, qfh[t2], qfl[t2]);
            }
        }

        f32x4 pvacc[NT];
        float sum[NT];
        #pragma unroll
        for (int t2 = 0; t2 < NT; ++t2) {
            pvacc[t2] = (f32x4){0.f,0.f,0.f,0.f};
            sum[t2] = 0.f;
        }

        // ---- key halves: only NH K/V frag tiles live at a time
        #pragma unroll 1
        for (int kh = 0; kh < 2; ++kh) {
            short4b kfh[NH], kfl[NH], vfh[NH], vfl[NH];
            {
                f32x4 aK[NH];
                #pragma unroll
                for (int t2 = 0; t2 < NH; ++t2) aK[t2] = (f32x4){0.f,0.f,0.f,0.f};
                #pragma unroll
                for (int kp = 0; kp < 4; ++kp) {
                    short8 wkh = *(const short8*)(Wh + ((8 + h) * 4 + kp) * 512 + l * 8);
                    short8 wkl = *(const short8*)(Wl + ((8 + h) * 4 + kp) * 512 + l * 8);
                    #pragma unroll
                    for (int tl = 0; tl < NH; ++tl) {
                        int tt = kh * NH + tl;
                        short8 xhv = *(const short8*)(xh + (tt * 4 + kp) * 512 + l * 8);
                        short8 xlv = *(const short8*)(xl + (tt * 4 + kp) * 512 + l * 8);
                        aK[tl] = __builtin_amdgcn_mfma_f32_16x16x32_bf16(wkh, xhv, aK[tl], 0, 0, 0);
                        aK[tl] = __builtin_amdgcn_mfma_f32_16x16x32_bf16(wkl, xhv, aK[tl], 0, 0, 0);
                        aK[tl] = __builtin_amdgcn_mfma_f32_16x16x32_bf16(wkh, xlv, aK[tl], 0, 0, 0);
                    }
                }
                #pragma unroll
                for (int tl = 0; tl < NH; ++tl) split4v(aK[tl], kfh[tl], kfl[tl]);
            }
            {
                f32x4 aV[NH];
                #pragma unroll
                for (int t2 = 0; t2 < NH; ++t2) aV[t2] = (f32x4){0.f,0.f,0.f,0.f};
                #pragma unroll
                for (int kp = 0; kp < 4; ++kp) {
                    short8 wvh = *(const short8*)(Wh + ((16 + h) * 4 + kp) * 512 + l * 8);
                    short8 wvl = *(const short8*)(Wl + ((16 + h) * 4 + kp) * 512 + l * 8);
                    #pragma unroll
                    for (int tl = 0; tl < NH; ++tl) {
                        int tt = kh * NH + tl;
                        short8 xhv = *(const short8*)(xh + (tt * 4 + kp) * 512 + l * 8);
                        short8 xlv = *(const short8*)(xl + (tt * 4 + kp) * 512 + l * 8);
                        aV[tl] = __builtin_amdgcn_mfma_f32_16x16x32_bf16(xhv, wvh, aV[tl], 0, 0, 0);
                        aV[tl] = __builtin_amdgcn_mfma_f32_16x16x32_bf16(xlv, wvh, aV[tl], 0, 0, 0);
                        aV[tl] = __builtin_amdgcn_mfma_f32_16x16x32_bf16(xhv, wvl, aV[tl], 0, 0, 0);
                    }
                }
                #pragma unroll
                for (int tl = 0; tl < NH; ++tl) split4v(aV[tl], vfh[tl], vfl[tl]);
            }

            // ---- partial attention over this key half
            #pragma unroll
            for (int it = 0; it < NT; ++it) {
                const int query = it * 16 + ic;
                const int qm = s_m[query];                   // padded: 0 for query >= N
                const unsigned msel = qm ? mbits : jbits;
                short4b ph[NH];
                #pragma unroll
                for (int jl = 0; jl < NH; ++jl) {
                    const int jt = kh * NH + jl;
                    f32x4 sa = (f32x4){0.f,0.f,0.f,0.f};
                    sa = __builtin_amdgcn_mfma_f32_16x16x16bf16_1k(kfh[jl], qfh[it], sa, 0, 0, 0);
                    sa = __builtin_amdgcn_mfma_f32_16x16x16bf16_1k(kfl[jl], qfh[it], sa, 0, 0, 0);
                    sa = __builtin_amdgcn_mfma_f32_16x16x16bf16_1k(kfh[jl], qfl[it], sa, 0, 0, 0);
                    #pragma unroll
                    for (int r = 0; r < 4; ++r) {
                        int bit = (jt << 2) + r;
                        float inner = qm ? sa[r] : 0.f;      // dead row: exp2(0)=1 over valid keys
                        float xv = ((msel >> bit) & 1u) ? inner : -1e30f;
                        float e = __builtin_amdgcn_exp2f(xv);
                        sum[it] += e;
                        unsigned ue = __float_as_uint(e);    // RNE to bf16
                        ue += 0x7fffu + ((ue >> 16) & 1u);
                        ph[jl][r] = (short)(ue >> 16);
                    }
                }
                #pragma unroll
                for (int jl = 0; jl < NH; ++jl) {
                    pvacc[it] = __builtin_amdgcn_mfma_f32_16x16x16bf16_1k(ph[jl], vfh[jl], pvacc[it], 0, 0, 0);
                    pvacc[it] = __builtin_amdgcn_mfma_f32_16x16x16bf16_1k(ph[jl], vfl[jl], pvacc[it], 0, 0, 0);
                }
            }
        }

        // ---- finalize: reduce sums, normalize, store
        #pragma unroll
        for (int it = 0; it < NT; ++it) {
            float ss = sum[it];
            ss += __shfl_xor(ss, 16, 64);
            ss += __shfl_xor(ss, 32, 64);
            const float inv = 1.f / ss;
            #pragma unroll
            for (int r = 0; r < 4; ++r) {
                int rloc = 4 * g + r;
                int row = it * 16 + rloc;
                int iv = __builtin_amdgcn_ds_bpermute(rloc << 2, __float_as_int(inv));
                if (FULL || row < N)
                    yws[((long)b * N + row) * C_ + h * HD_ + ic] = pvacc[it][r] * __int_as_float(iv);
            }
        }
    }
}

// ---------------------------------------------------------------------------
// K2: proj GEMM (round-12-proven). Block = 64 rows x 128 cols, 4 waves;
// A = f32 rows from ws, split in-reg; B = pre-split proj weights
// (PASS-selected in device code); 3-term split MFMA; f32 out + bias.
// ---------------------------------------------------------------------------
template<int PASS>
__global__ __launch_bounds__(256) void proj_gemm(
    const float* __restrict__ A, const float* __restrict__ bias,
    float* __restrict__ out)
{
    const short* Ph = (PASS == 0) ? g_wpa_h : g_wpt_h;
    const short* Pl = (PASS == 0) ? g_wpa_l : g_wpt_l;

    const int tid = threadIdx.x;
    const int w = tid >> 6, l = tid & 63;
    const int rl = l & 15, g = l >> 4;
    const int lr0 = blockIdx.x * 64 + w * 16;
    const float* arow = A + (long)(lr0 + rl) * C_ + g * 8;

    f32x4 acc[8];
    #pragma unroll
    for (int i = 0; i < 8; ++i) acc[i] = (f32x4){0.f, 0.f, 0.f, 0.f};

    #pragma unroll
    for (int kp = 0; kp < 4; ++kp) {
        short8 ah, al;
        split8g(arow + kp * 32, ah, al);
        #pragma unroll
        for (int ct = 0; ct < 8; ++ct) {
            short8 bh  = *(const short8*)(Ph + (ct * 4 + kp) * 512 + l * 8);
            short8 blo = *(const short8*)(Pl + (ct * 4 + kp) * 512 + l * 8);
            acc[ct] = __builtin_amdgcn_mfma_f32_16x16x32_bf16(ah, bh, acc[ct], 0, 0, 0);
            acc[ct] = __builtin_amdgcn_mfma_f32_16x16x32_bf16(al, bh, acc[ct], 0, 0, 0);
            acc[ct] = __builtin_amdgcn_mfma_f32_16x16x32_bf16(ah, blo, acc[ct], 0, 0, 0);
        }
    }

    #pragma unroll
    for (int ct = 0; ct < 8; ++ct) {
        int cc = ct * 16 + rl;
        float bv = bias[cc];
        #pragma unroll
        for (int r = 0; r < 4; ++r)
            out[(long)(lr0 + g * 4 + r) * C_ + cc] = acc[ct][r] + bv;
    }
}

extern "C" void kernel_launch(void* const* d_in, const int* in_sizes, int n_in,
                              void* d_out, int out_size, void* d_ws, size_t ws_size,
                              hipStream_t stream) {
    const float* x       = (const float*)d_in[0];
    const int*   mask    = (const int*)d_in[1];
    const float* Wqkv_a  = (const float*)d_in[2];
    const float* Wproj_a = (const float*)d_in[3];
    const float* bproj_a = (const float*)d_in[4];
    const float* Wqkv_t  = (const float*)d_in[5];
    const float* Wproj_t = (const float*)d_in[6];
    const float* bproj_t = (const float*)d_in[7];
    float* out = (float*)d_out;
    float* yws = (float*)d_ws;   // pre-proj y, f32, 186368 x 128 = 95,420,416 B

    prep_all<<<64, 256, 0, stream>>>(Wqkv_a, Wqkv_t, Wproj_a, Wproj_t);

    const int NROWTILES = S_ * O_ * T_ / 64;   // 2912 blocks of 64 rows

    // ---- Pass 1: agent attention. batch (s,t), tokens = objects (N=64, NT=4).
    // attn: x -> yws (f32). proj: yws -> d_out as xa(s,t,o,c) (identity rows).
    {
        const size_t lds = 4 * 8192 + 4 * 64;
        attn_pass<O_, 4, 0><<<S_ * T_, 256, lds, stream>>>(
            x, mask, yws,
            T_, (long)O_ * T_ * C_, (long)C_, (long)T_ * C_,
            1L, (long)T_);
        proj_gemm<0><<<NROWTILES, 256, 0, stream>>>(yws, bproj_a, out);
    }
    // ---- Pass 2: time attention. batch (s,o), tokens = timesteps (N=91, NT=6).
    // attn: reads xa from d_out, writes yws. proj: yws -> d_out final (s,o,t,c).
    {
        const size_t lds = 6 * 8192 + 6 * 64;
        attn_pass<T_, 6, 1><<<S_ * O_, 256, lds, stream>>>(
            out, mask, yws,
            O_, (long)T_ * O_ * C_, (long)C_, (long)O_ * C_,
            (long)T_, 1L);
        proj_gemm<1><<<NROWTILES, 256, 0, stream>>>(yws, bproj_t, out);
    }
}

// Round 14
// 330.987 us; speedup vs baseline: 2.9086x; 2.9086x over previous
//
#include <hip/hip_runtime.h>

#define S_ 32
#define O_ 64
#define T_ 91
#define C_ 128
#define H_ 8
#define HD_ 16

typedef __attribute__((ext_vector_type(8))) short short8;
typedef __attribute__((ext_vector_type(4))) short short4b;
typedef __attribute__((ext_vector_type(4))) float f32x4;

// Pre-split weights (bf16 hi/lo, MFMA-frag-linear), written by prep_all each call.
__device__ short g_wqa_h[384 * 128], g_wqa_l[384 * 128];
__device__ short g_wqt_h[384 * 128], g_wqt_l[384 * 128];
__device__ short g_wpa_h[128 * 128], g_wpa_l[128 * 128];
__device__ short g_wpt_h[128 * 128], g_wpt_l[128 * 128];

__device__ __forceinline__ void splitf(float f, short& h, short& l) {
    unsigned u = __float_as_uint(f);
    float hf = __uint_as_float(u & 0xffff0000u);
    h = (short)(u >> 16);
    l = (short)(__float_as_uint(f - hf) >> 16);
}

__device__ __forceinline__ void split8g(const float* p, short8& h, short8& l) {
    float4 a = *(const float4*)p;
    float4 b = *(const float4*)(p + 4);
    float v[8] = {a.x, a.y, a.z, a.w, b.x, b.y, b.z, b.w};
    #pragma unroll
    for (int j = 0; j < 8; ++j) { short hh, ll; splitf(v[j], hh, ll); h[j] = hh; l[j] = ll; }
}

__device__ __forceinline__ void split4v(f32x4 v, short4b& h, short4b& l) {
    #pragma unroll
    for (int j = 0; j < 4; ++j) { short hh, ll; splitf(v[j], hh, ll); h[j] = hh; l[j] = ll; }
}

// ---------------------------------------------------------------------------
// Weight prep: all four matrices -> hi/lo bf16, frag-linear:
// element (c,k): ct=c>>4, cl=c&15, kp=k>>5, gg=(k>>3)&3, j=k&7
//   slot = ct*2048 + kp*512 + (cl+16*gg)*8 + j
// ---------------------------------------------------------------------------
__global__ __launch_bounds__(256) void prep_all(
    const float* __restrict__ wqa, const float* __restrict__ wqt,
    const float* __restrict__ wpa, const float* __restrict__ wpt)
{
    int t = blockIdx.x * 256 + threadIdx.x;     // 16384 total
    const float* src; short* dh; short* dl; int idx;
    if (t < 6144)       { src = wqa; dh = g_wqa_h; dl = g_wqa_l; idx = t; }
    else if (t < 12288) { src = wqt; dh = g_wqt_h; dl = g_wqt_l; idx = t - 6144; }
    else if (t < 14336) { src = wpa; dh = g_wpa_h; dl = g_wpa_l; idx = t - 12288; }
    else                { src = wpt; dh = g_wpt_h; dl = g_wpt_l; idx = t - 14336; }
    int c = idx >> 4, gk = idx & 15;
    int kp = gk >> 2, gg = gk & 3;
    int ct = c >> 4, cl = c & 15;
    const float* s = src + (long)c * C_ + gk * 8;
    long slot = (long)ct * 2048 + kp * 512 + (cl + 16 * gg) * 8;
    short8 vh, vl;
    split8g(s, vh, vl);
    *(short8*)(dh + slot) = vh;
    *(short8*)(dl + slot) = vl;
}

// ---------------------------------------------------------------------------
// K1: QKV + masked attention. HEAD-SPLIT blocks (round-13 lesson: any
// min-waves launch-bound on this kernel spills; instead shrink natural reg
// need and let two/three independent blocks co-reside):
//   grid = (batches, 2); block = 256 thr = 4 waves; wave wv owns head
//   h = blockIdx.y*4 + wv. Q, K, V computed in three separate sweeps so only
//   one accumulator set (24 regs) is live at a time; peak ~150 regs, NO
//   launch bound. y (f32, normalized) streamed to ws row-major.
// ---------------------------------------------------------------------------
template<int N, int NT, int PASS>
__global__ __launch_bounds__(256) void attn_pass(
    const float* __restrict__ xg, const int* __restrict__ mask,
    float* __restrict__ yws,
    int bdiv, long bs1, long bs2, long ts, long m1, long m2)
{
    constexpr bool FULL = (NT * 16 == N);
    extern __shared__ char smem[];
    short* xh = (short*)smem;                       // NT*2048 shorts
    short* xl = xh + NT * 2048;                     // NT*2048 shorts
    int*   s_m = (int*)(smem + NT * 8192);          // NT*16 ints

    const short* Wh = (PASS == 0) ? g_wqa_h : g_wqt_h;
    const short* Wl = (PASS == 0) ? g_wqa_l : g_wqt_l;

    const int tid = threadIdx.x;
    const int wv = tid >> 6, l = tid & 63;
    const int ic = l & 15, g = l >> 4;
    const int b = blockIdx.x;
    const int h = blockIdx.y * 4 + wv;              // head for this wave
    const int s = b / bdiv, u = b - s * bdiv;
    const long xbase = (long)s * bs1 + (long)u * bs2;
    const long mbase = (long)s * (O_ * T_) + (long)u * m1;

    // ---- Stage 0: stage x (split, frag-linear) + mask
    for (int gi = tid; gi < NT * 256; gi += 256) {
        int token = gi >> 4, cg = gi & 15;
        int kp = cg >> 2, gg = cg & 3;
        int slot = ((token >> 4) * 4 + kp) * 512 + (gg * 16 + (token & 15)) * 8;
        short8 vh, vl;
        if (FULL || token < N) {
            split8g(xg + xbase + (long)token * ts + cg * 8, vh, vl);
        } else {
            #pragma unroll
            for (int j = 0; j < 8; ++j) { vh[j] = 0; vl[j] = 0; }
        }
        *(short8*)(xh + slot) = vh;
        *(short8*)(xl + slot) = vl;
    }
    for (int idx = tid; idx < NT * 16; idx += 256)
        s_m[idx] = (idx < N) ? (mask[mbase + (long)idx * m2] != 0) : 0;
    __syncthreads();

    // per-lane key bitmasks: key j = jt*16 + 4g + r -> bit jt*4+r
    unsigned jbits = 0, mbits = 0;
    #pragma unroll
    for (int jt = 0; jt < NT; ++jt)
        #pragma unroll
        for (int r = 0; r < 4; ++r) {
            int j = jt * 16 + 4 * g + r;
            if (j < N) {
                jbits |= 1u << (jt * 4 + r);
                if (s_m[j]) mbits |= 1u << (jt * 4 + r);
            }
        }

    const float QS = 0.25f * 1.44269504088896f;   // softmax scale * log2(e), folded into Q

    // ---- Sweep 1: Q frags
    short4b qfh[NT], qfl[NT];
    {
        f32x4 aQ[NT];
        #pragma unroll
        for (int t2 = 0; t2 < NT; ++t2) aQ[t2] = (f32x4){0.f,0.f,0.f,0.f};
        #pragma unroll
        for (int kp = 0; kp < 4; ++kp) {
            short8 wqh = *(const short8*)(Wh + (h * 4 + kp) * 512 + l * 8);
            short8 wql = *(const short8*)(Wl + (h * 4 + kp) * 512 + l * 8);
            #pragma unroll
            for (int tt = 0; tt < NT; ++tt) {
                short8 xhv = *(const short8*)(xh + (tt * 4 + kp) * 512 + l * 8);
                short8 xlv = *(const short8*)(xl + (tt * 4 + kp) * 512 + l * 8);
                aQ[tt] = __builtin_amdgcn_mfma_f32_16x16x32_bf16(wqh, xhv, aQ[tt], 0, 0, 0);
                aQ[tt] = __builtin_amdgcn_mfma_f32_16x16x32_bf16(wql, xhv, aQ[tt], 0, 0, 0);
                aQ[tt] = __builtin_amdgcn_mfma_f32_16x16x32_bf16(wqh, xlv, aQ[tt], 0, 0, 0);
            }
        }
        #pragma unroll
        for (int t2 = 0; t2 < NT; ++t2) {
            f32x4 qs = aQ[t2] * QS;
            split4v(qs, qfh[t2], qfl[t2]);
        }
    }
    // ---- Sweep 2: K frags
    short4b kfh[NT], kfl[NT];
    {
        f32x4 aK[NT];
        #pragma unroll
        for (int t2 = 0; t2 < NT; ++t2) aK[t2] = (f32x4){0.f,0.f,0.f,0.f};
        #pragma unroll
        for (int kp = 0; kp < 4; ++kp) {
            short8 wkh = *(const short8*)(Wh + ((8 + h) * 4 + kp) * 512 + l * 8);
            short8 wkl = *(const short8*)(Wl + ((8 + h) * 4 + kp) * 512 + l * 8);
            #pragma unroll
            for (int tt = 0; tt < NT; ++tt) {
                short8 xhv = *(const short8*)(xh + (tt * 4 + kp) * 512 + l * 8);
                short8 xlv = *(const short8*)(xl + (tt * 4 + kp) * 512 + l * 8);
                aK[tt] = __builtin_amdgcn_mfma_f32_16x16x32_bf16(wkh, xhv, aK[tt], 0, 0, 0);
                aK[tt] = __builtin_amdgcn_mfma_f32_16x16x32_bf16(wkl, xhv, aK[tt], 0, 0, 0);
                aK[tt] = __builtin_amdgcn_mfma_f32_16x16x32_bf16(wkh, xlv, aK[tt], 0, 0, 0);
            }
        }
        #pragma unroll
        for (int t2 = 0; t2 < NT; ++t2) split4v(aK[t2], kfh[t2], kfl[t2]);
    }
    // ---- Sweep 3: V frags
    short4b vfh[NT], vfl[NT];
    {
        f32x4 aV[NT];
        #pragma unroll
        for (int t2 = 0; t2 < NT; ++t2) aV[t2] = (f32x4){0.f,0.f,0.f,0.f};
        #pragma unroll
        for (int kp = 0; kp < 4; ++kp) {
            short8 wvh = *(const short8*)(Wh + ((16 + h) * 4 + kp) * 512 + l * 8);
            short8 wvl = *(const short8*)(Wl + ((16 + h) * 4 + kp) * 512 + l * 8);
            #pragma unroll
            for (int tt = 0; tt < NT; ++tt) {
                short8 xhv = *(const short8*)(xh + (tt * 4 + kp) * 512 + l * 8);
                short8 xlv = *(const short8*)(xl + (tt * 4 + kp) * 512 + l * 8);
                aV[tt] = __builtin_amdgcn_mfma_f32_16x16x32_bf16(xhv, wvh, aV[tt], 0, 0, 0);
                aV[tt] = __builtin_amdgcn_mfma_f32_16x16x32_bf16(xlv, wvh, aV[tt], 0, 0, 0);
                aV[tt] = __builtin_amdgcn_mfma_f32_16x16x32_bf16(xhv, wvl, aV[tt], 0, 0, 0);
            }
        }
        #pragma unroll
        for (int t2 = 0; t2 < NT; ++t2) split4v(aV[t2], vfh[t2], vfl[t2]);
    }

    // ---- Stage 2: attention; y (f32, normalized) streamed to ws
    #pragma unroll
    for (int it = 0; it < NT; ++it) {
        const int query = it * 16 + ic;
        const int qm = s_m[query];                   // padded: 0 for query >= N
        const unsigned msel = qm ? mbits : jbits;
        float sum = 0.f;
        short4b ph[NT];
        #pragma unroll
        for (int jt = 0; jt < NT; ++jt) {
            f32x4 sa = (f32x4){0.f,0.f,0.f,0.f};
            sa = __builtin_amdgcn_mfma_f32_16x16x16bf16_1k(kfh[jt], qfh[it], sa, 0, 0, 0);
            sa = __builtin_amdgcn_mfma_f32_16x16x16bf16_1k(kfl[jt], qfh[it], sa, 0, 0, 0);
            sa = __builtin_amdgcn_mfma_f32_16x16x16bf16_1k(kfh[jt], qfl[it], sa, 0, 0, 0);
            #pragma unroll
            for (int r = 0; r < 4; ++r) {
                int bit = (jt << 2) + r;
                float inner = qm ? sa[r] : 0.f;      // dead row: exp2(0)=1 over valid keys
                float xv = ((msel >> bit) & 1u) ? inner : -1e30f;
                float e = __builtin_amdgcn_exp2f(xv);
                sum += e;
                unsigned ue = __float_as_uint(e);    // RNE to bf16
                ue += 0x7fffu + ((ue >> 16) & 1u);
                ph[jt][r] = (short)(ue >> 16);
            }
        }
        sum += __shfl_xor(sum, 16, 64);
        sum += __shfl_xor(sum, 32, 64);
        const float inv = 1.f / sum;

        // PV with two accumulators (NT is even)
        f32x4 pv0 = (f32x4){0.f,0.f,0.f,0.f};
        f32x4 pv1 = (f32x4){0.f,0.f,0.f,0.f};
        #pragma unroll
        for (int kt = 0; kt < NT; kt += 2) {
            pv0 = __builtin_amdgcn_mfma_f32_16x16x16bf16_1k(ph[kt], vfh[kt], pv0, 0, 0, 0);
            pv0 = __builtin_amdgcn_mfma_f32_16x16x16bf16_1k(ph[kt], vfl[kt], pv0, 0, 0, 0);
            pv1 = __builtin_amdgcn_mfma_f32_16x16x16bf16_1k(ph[kt+1], vfh[kt+1], pv1, 0, 0, 0);
            pv1 = __builtin_amdgcn_mfma_f32_16x16x16bf16_1k(ph[kt+1], vfl[kt+1], pv1, 0, 0, 0);
        }
        f32x4 pv = pv0 + pv1;
        #pragma unroll
        for (int r = 0; r < 4; ++r) {
            int rloc = 4 * g + r;
            int row = it * 16 + rloc;
            int iv = __builtin_amdgcn_ds_bpermute(rloc << 2, __float_as_int(inv));
            if (FULL || row < N)
                yws[((long)b * N + row) * C_ + h * HD_ + ic] = pv[r] * __int_as_float(iv);
        }
    }
}

// ---------------------------------------------------------------------------
// K2: proj GEMM (round-12/13-proven). Block = 64 rows x 128 cols, 4 waves;
// A = f32 rows from ws, split in-reg; B = pre-split proj weights
// (PASS-selected in device code); 3-term split MFMA; f32 out + bias.
// ---------------------------------------------------------------------------
template<int PASS>
__global__ __launch_bounds__(256) void proj_gemm(
    const float* __restrict__ A, const float* __restrict__ bias,
    float* __restrict__ out)
{
    const short* Ph = (PASS == 0) ? g_wpa_h : g_wpt_h;
    const short* Pl = (PASS == 0) ? g_wpa_l : g_wpt_l;

    const int tid = threadIdx.x;
    const int w = tid >> 6, l = tid & 63;
    const int rl = l & 15, g = l >> 4;
    const int lr0 = blockIdx.x * 64 + w * 16;
    const float* arow = A + (long)(lr0 + rl) * C_ + g * 8;

    f32x4 acc[8];
    #pragma unroll
    for (int i = 0; i < 8; ++i) acc[i] = (f32x4){0.f, 0.f, 0.f, 0.f};

    #pragma unroll
    for (int kp = 0; kp < 4; ++kp) {
        short8 ah, al;
        split8g(arow + kp * 32, ah, al);
        #pragma unroll
        for (int ct = 0; ct < 8; ++ct) {
            short8 bh  = *(const short8*)(Ph + (ct * 4 + kp) * 512 + l * 8);
            short8 blo = *(const short8*)(Pl + (ct * 4 + kp) * 512 + l * 8);
            acc[ct] = __builtin_amdgcn_mfma_f32_16x16x32_bf16(ah, bh, acc[ct], 0, 0, 0);
            acc[ct] = __builtin_amdgcn_mfma_f32_16x16x32_bf16(al, bh, acc[ct], 0, 0, 0);
            acc[ct] = __builtin_amdgcn_mfma_f32_16x16x32_bf16(ah, blo, acc[ct], 0, 0, 0);
        }
    }

    #pragma unroll
    for (int ct = 0; ct < 8; ++ct) {
        int cc = ct * 16 + rl;
        float bv = bias[cc];
        #pragma unroll
        for (int r = 0; r < 4; ++r)
            out[(long)(lr0 + g * 4 + r) * C_ + cc] = acc[ct][r] + bv;
    }
}

extern "C" void kernel_launch(void* const* d_in, const int* in_sizes, int n_in,
                              void* d_out, int out_size, void* d_ws, size_t ws_size,
                              hipStream_t stream) {
    const float* x       = (const float*)d_in[0];
    const int*   mask    = (const int*)d_in[1];
    const float* Wqkv_a  = (const float*)d_in[2];
    const float* Wproj_a = (const float*)d_in[3];
    const float* bproj_a = (const float*)d_in[4];
    const float* Wqkv_t  = (const float*)d_in[5];
    const float* Wproj_t = (const float*)d_in[6];
    const float* bproj_t = (const float*)d_in[7];
    float* out = (float*)d_out;
    float* yws = (float*)d_ws;   // pre-proj y, f32, 186368 x 128 = 95,420,416 B

    prep_all<<<64, 256, 0, stream>>>(Wqkv_a, Wqkv_t, Wproj_a, Wproj_t);

    const int NROWTILES = S_ * O_ * T_ / 64;   // 2912 blocks of 64 rows

    // ---- Pass 1: agent attention. batch (s,t), tokens = objects (N=64, NT=4).
    // attn: x -> yws (f32). proj: yws -> d_out as xa(s,t,o,c) (identity rows).
    {
        const size_t lds = 4 * 8192 + 4 * 64;
        attn_pass<O_, 4, 0><<<dim3(S_ * T_, 2), 256, lds, stream>>>(
            x, mask, yws,
            T_, (long)O_ * T_ * C_, (long)C_, (long)T_ * C_,
            1L, (long)T_);
        proj_gemm<0><<<NROWTILES, 256, 0, stream>>>(yws, bproj_a, out);
    }
    // ---- Pass 2: time attention. batch (s,o), tokens = timesteps (N=91, NT=6).
    // attn: reads xa from d_out, writes yws. proj: yws -> d_out final (s,o,t,c).
    {
        const size_t lds = 6 * 8192 + 6 * 64;
        attn_pass<T_, 6, 1><<<dim3(S_ * O_, 2), 256, lds, stream>>>(
            out, mask, yws,
            O_, (long)T_ * O_ * C_, (long)C_, (long)O_ * C_,
            (long)T_, 1L);
        proj_gemm<1><<<NROWTILES, 256, 0, stream>>>(yws, bproj_t, out);
    }
}

// Round 15
// 328.149 us; speedup vs baseline: 2.9337x; 1.0086x over previous
//
#include <hip/hip_runtime.h>

#define S_ 32
#define O_ 64
#define T_ 91
#define C_ 128
#define H_ 8
#define HD_ 16

typedef __attribute__((ext_vector_type(8))) short short8;
typedef __attribute__((ext_vector_type(4))) short short4b;
typedef __attribute__((ext_vector_type(4))) float f32x4;

// Pre-split weights (bf16 hi/lo, MFMA-frag-linear), written by prep_all each call.
__device__ short g_wqa_h[384 * 128], g_wqa_l[384 * 128];
__device__ short g_wqt_h[384 * 128], g_wqt_l[384 * 128];
__device__ short g_wpa_h[128 * 128], g_wpa_l[128 * 128];
__device__ short g_wpt_h[128 * 128], g_wpt_l[128 * 128];

__device__ __forceinline__ void splitf(float f, short& h, short& l) {
    unsigned u = __float_as_uint(f);
    float hf = __uint_as_float(u & 0xffff0000u);
    h = (short)(u >> 16);
    l = (short)(__float_as_uint(f - hf) >> 16);
}

__device__ __forceinline__ void split8g(const float* p, short8& h, short8& l) {
    float4 a = *(const float4*)p;
    float4 b = *(const float4*)(p + 4);
    float v[8] = {a.x, a.y, a.z, a.w, b.x, b.y, b.z, b.w};
    #pragma unroll
    for (int j = 0; j < 8; ++j) { short hh, ll; splitf(v[j], hh, ll); h[j] = hh; l[j] = ll; }
}

__device__ __forceinline__ void split4v(f32x4 v, short4b& h, short4b& l) {
    #pragma unroll
    for (int j = 0; j < 4; ++j) { short hh, ll; splitf(v[j], hh, ll); h[j] = hh; l[j] = ll; }
}

// RNE round f32x4 -> 4x bf16 (single precision level, no low part)
__device__ __forceinline__ short4b rne4(f32x4 v) {
    short4b o;
    #pragma unroll
    for (int j = 0; j < 4; ++j) {
        unsigned ue = __float_as_uint(v[j]);
        ue += 0x7fffu + ((ue >> 16) & 1u);
        o[j] = (short)(ue >> 16);
    }
    return o;
}

// ---------------------------------------------------------------------------
// Weight prep: all four matrices -> hi/lo bf16, frag-linear:
// element (c,k): ct=c>>4, cl=c&15, kp=k>>5, gg=(k>>3)&3, j=k&7
//   slot = ct*2048 + kp*512 + (cl+16*gg)*8 + j
// ---------------------------------------------------------------------------
__global__ __launch_bounds__(256) void prep_all(
    const float* __restrict__ wqa, const float* __restrict__ wqt,
    const float* __restrict__ wpa, const float* __restrict__ wpt)
{
    int t = blockIdx.x * 256 + threadIdx.x;     // 16384 total
    const float* src; short* dh; short* dl; int idx;
    if (t < 6144)       { src = wqa; dh = g_wqa_h; dl = g_wqa_l; idx = t; }
    else if (t < 12288) { src = wqt; dh = g_wqt_h; dl = g_wqt_l; idx = t - 6144; }
    else if (t < 14336) { src = wpa; dh = g_wpa_h; dl = g_wpa_l; idx = t - 12288; }
    else                { src = wpt; dh = g_wpt_h; dl = g_wpt_l; idx = t - 14336; }
    int c = idx >> 4, gk = idx & 15;
    int kp = gk >> 2, gg = gk & 3;
    int ct = c >> 4, cl = c & 15;
    const float* s = src + (long)c * C_ + gk * 8;
    long slot = (long)ct * 2048 + kp * 512 + (cl + 16 * gg) * 8;
    short8 vh, vl;
    split8g(s, vh, vl);
    *(short8*)(dh + slot) = vh;
    *(short8*)(dl + slot) = vl;
}

// ---------------------------------------------------------------------------
// K1: QKV + masked attention. HEAD-SPLIT blocks (round-14-proven, no launch
// bound -> no spills): grid = (batches, 2); block = 256 thr = 4 waves; wave
// wv owns head h = blockIdx.y*4 + wv. Q, K, V in three sweeps separated by
// sched_barrier(0) (limits cross-sweep hoisting -> lower live-reg peak).
// Round-15 cuts: V kept as single RNE bf16 (PV halves, -12 regs); PV
// interleaved into the jt loop (ph single tile, -10 regs).
// y (f32, normalized) streamed to ws row-major.
// ---------------------------------------------------------------------------
template<int N, int NT, int PASS>
__global__ __launch_bounds__(256) void attn_pass(
    const float* __restrict__ xg, const int* __restrict__ mask,
    float* __restrict__ yws,
    int bdiv, long bs1, long bs2, long ts, long m1, long m2)
{
    constexpr bool FULL = (NT * 16 == N);
    extern __shared__ char smem[];
    short* xh = (short*)smem;                       // NT*2048 shorts
    short* xl = xh + NT * 2048;                     // NT*2048 shorts
    int*   s_m = (int*)(smem + NT * 8192);          // NT*16 ints

    const short* Wh = (PASS == 0) ? g_wqa_h : g_wqt_h;
    const short* Wl = (PASS == 0) ? g_wqa_l : g_wqt_l;

    const int tid = threadIdx.x;
    const int wv = tid >> 6, l = tid & 63;
    const int ic = l & 15, g = l >> 4;
    const int b = blockIdx.x;
    const int h = blockIdx.y * 4 + wv;              // head for this wave
    const int s = b / bdiv, u = b - s * bdiv;
    const long xbase = (long)s * bs1 + (long)u * bs2;
    const long mbase = (long)s * (O_ * T_) + (long)u * m1;

    // ---- Stage 0: stage x (split, frag-linear) + mask
    for (int gi = tid; gi < NT * 256; gi += 256) {
        int token = gi >> 4, cg = gi & 15;
        int kp = cg >> 2, gg = cg & 3;
        int slot = ((token >> 4) * 4 + kp) * 512 + (gg * 16 + (token & 15)) * 8;
        short8 vh, vl;
        if (FULL || token < N) {
            split8g(xg + xbase + (long)token * ts + cg * 8, vh, vl);
        } else {
            #pragma unroll
            for (int j = 0; j < 8; ++j) { vh[j] = 0; vl[j] = 0; }
        }
        *(short8*)(xh + slot) = vh;
        *(short8*)(xl + slot) = vl;
    }
    for (int idx = tid; idx < NT * 16; idx += 256)
        s_m[idx] = (idx < N) ? (mask[mbase + (long)idx * m2] != 0) : 0;
    __syncthreads();

    // per-lane key bitmasks: key j = jt*16 + 4g + r -> bit jt*4+r
    unsigned jbits = 0, mbits = 0;
    #pragma unroll
    for (int jt = 0; jt < NT; ++jt)
        #pragma unroll
        for (int r = 0; r < 4; ++r) {
            int j = jt * 16 + 4 * g + r;
            if (j < N) {
                jbits |= 1u << (jt * 4 + r);
                if (s_m[j]) mbits |= 1u << (jt * 4 + r);
            }
        }

    const float QS = 0.25f * 1.44269504088896f;   // softmax scale * log2(e), folded into Q

    // ---- Sweep 1: Q frags
    short4b qfh[NT], qfl[NT];
    {
        f32x4 aQ[NT];
        #pragma unroll
        for (int t2 = 0; t2 < NT; ++t2) aQ[t2] = (f32x4){0.f,0.f,0.f,0.f};
        #pragma unroll
        for (int kp = 0; kp < 4; ++kp) {
            short8 wqh = *(const short8*)(Wh + (h * 4 + kp) * 512 + l * 8);
            short8 wql = *(const short8*)(Wl + (h * 4 + kp) * 512 + l * 8);
            #pragma unroll
            for (int tt = 0; tt < NT; ++tt) {
                short8 xhv = *(const short8*)(xh + (tt * 4 + kp) * 512 + l * 8);
                short8 xlv = *(const short8*)(xl + (tt * 4 + kp) * 512 + l * 8);
                aQ[tt] = __builtin_amdgcn_mfma_f32_16x16x32_bf16(wqh, xhv, aQ[tt], 0, 0, 0);
                aQ[tt] = __builtin_amdgcn_mfma_f32_16x16x32_bf16(wql, xhv, aQ[tt], 0, 0, 0);
                aQ[tt] = __builtin_amdgcn_mfma_f32_16x16x32_bf16(wqh, xlv, aQ[tt], 0, 0, 0);
            }
        }
        #pragma unroll
        for (int t2 = 0; t2 < NT; ++t2) {
            f32x4 qs = aQ[t2] * QS;
            split4v(qs, qfh[t2], qfl[t2]);
        }
    }
    __builtin_amdgcn_sched_barrier(0);
    // ---- Sweep 2: K frags
    short4b kfh[NT], kfl[NT];
    {
        f32x4 aK[NT];
        #pragma unroll
        for (int t2 = 0; t2 < NT; ++t2) aK[t2] = (f32x4){0.f,0.f,0.f,0.f};
        #pragma unroll
        for (int kp = 0; kp < 4; ++kp) {
            short8 wkh = *(const short8*)(Wh + ((8 + h) * 4 + kp) * 512 + l * 8);
            short8 wkl = *(const short8*)(Wl + ((8 + h) * 4 + kp) * 512 + l * 8);
            #pragma unroll
            for (int tt = 0; tt < NT; ++tt) {
                short8 xhv = *(const short8*)(xh + (tt * 4 + kp) * 512 + l * 8);
                short8 xlv = *(const short8*)(xl + (tt * 4 + kp) * 512 + l * 8);
                aK[tt] = __builtin_amdgcn_mfma_f32_16x16x32_bf16(wkh, xhv, aK[tt], 0, 0, 0);
                aK[tt] = __builtin_amdgcn_mfma_f32_16x16x32_bf16(wkl, xhv, aK[tt], 0, 0, 0);
                aK[tt] = __builtin_amdgcn_mfma_f32_16x16x32_bf16(wkh, xlv, aK[tt], 0, 0, 0);
            }
        }
        #pragma unroll
        for (int t2 = 0; t2 < NT; ++t2) split4v(aK[t2], kfh[t2], kfl[t2]);
    }
    __builtin_amdgcn_sched_barrier(0);
    // ---- Sweep 3: V frags (single RNE bf16 -- PV term halving, round 15)
    short4b vfr[NT];
    {
        f32x4 aV[NT];
        #pragma unroll
        for (int t2 = 0; t2 < NT; ++t2) aV[t2] = (f32x4){0.f,0.f,0.f,0.f};
        #pragma unroll
        for (int kp = 0; kp < 4; ++kp) {
            short8 wvh = *(const short8*)(Wh + ((16 + h) * 4 + kp) * 512 + l * 8);
            short8 wvl = *(const short8*)(Wl + ((16 + h) * 4 + kp) * 512 + l * 8);
            #pragma unroll
            for (int tt = 0; tt < NT; ++tt) {
                short8 xhv = *(const short8*)(xh + (tt * 4 + kp) * 512 + l * 8);
                short8 xlv = *(const short8*)(xl + (tt * 4 + kp) * 512 + l * 8);
                aV[tt] = __builtin_amdgcn_mfma_f32_16x16x32_bf16(xhv, wvh, aV[tt], 0, 0, 0);
                aV[tt] = __builtin_amdgcn_mfma_f32_16x16x32_bf16(xlv, wvh, aV[tt], 0, 0, 0);
                aV[tt] = __builtin_amdgcn_mfma_f32_16x16x32_bf16(xhv, wvl, aV[tt], 0, 0, 0);
            }
        }
        #pragma unroll
        for (int t2 = 0; t2 < NT; ++t2) vfr[t2] = rne4(aV[t2]);
    }
    __builtin_amdgcn_sched_barrier(0);

    // ---- Stage 2: attention; PV interleaved per key-tile; y streamed to ws
    #pragma unroll
    for (int it = 0; it < NT; ++it) {
        const int query = it * 16 + ic;
        const int qm = s_m[query];                   // padded: 0 for query >= N
        const unsigned msel = qm ? mbits : jbits;
        float sum = 0.f;
        f32x4 pv0 = (f32x4){0.f,0.f,0.f,0.f};
        f32x4 pv1 = (f32x4){0.f,0.f,0.f,0.f};
        #pragma unroll
        for (int jt = 0; jt < NT; ++jt) {
            f32x4 sa = (f32x4){0.f,0.f,0.f,0.f};
            sa = __builtin_amdgcn_mfma_f32_16x16x16bf16_1k(kfh[jt], qfh[it], sa, 0, 0, 0);
            sa = __builtin_amdgcn_mfma_f32_16x16x16bf16_1k(kfl[jt], qfh[it], sa, 0, 0, 0);
            sa = __builtin_amdgcn_mfma_f32_16x16x16bf16_1k(kfh[jt], qfl[it], sa, 0, 0, 0);
            short4b ph;
            #pragma unroll
            for (int r = 0; r < 4; ++r) {
                int bit = (jt << 2) + r;
                float inner = qm ? sa[r] : 0.f;      // dead row: exp2(0)=1 over valid keys
                float xv = ((msel >> bit) & 1u) ? inner : -1e30f;
                float e = __builtin_amdgcn_exp2f(xv);
                sum += e;
                unsigned ue = __float_as_uint(e);    // RNE to bf16
                ue += 0x7fffu + ((ue >> 16) & 1u);
                ph[r] = (short)(ue >> 16);
            }
            if (jt & 1)
                pv1 = __builtin_amdgcn_mfma_f32_16x16x16bf16_1k(ph, vfr[jt], pv1, 0, 0, 0);
            else
                pv0 = __builtin_amdgcn_mfma_f32_16x16x16bf16_1k(ph, vfr[jt], pv0, 0, 0, 0);
        }
        sum += __shfl_xor(sum, 16, 64);
        sum += __shfl_xor(sum, 32, 64);
        const float inv = 1.f / sum;

        f32x4 pv = pv0 + pv1;
        #pragma unroll
        for (int r = 0; r < 4; ++r) {
            int rloc = 4 * g + r;
            int row = it * 16 + rloc;
            int iv = __builtin_amdgcn_ds_bpermute(rloc << 2, __float_as_int(inv));
            if (FULL || row < N)
                yws[((long)b * N + row) * C_ + h * HD_ + ic] = pv[r] * __int_as_float(iv);
        }
    }
}

// ---------------------------------------------------------------------------
// K2: proj GEMM (round-12..14-proven). Block = 64 rows x 128 cols, 4 waves;
// A = f32 rows from ws, split in-reg; B = pre-split proj weights
// (PASS-selected in device code); 3-term split MFMA; f32 out + bias.
// ---------------------------------------------------------------------------
template<int PASS>
__global__ __launch_bounds__(256) void proj_gemm(
    const float* __restrict__ A, const float* __restrict__ bias,
    float* __restrict__ out)
{
    const short* Ph = (PASS == 0) ? g_wpa_h : g_wpt_h;
    const short* Pl = (PASS == 0) ? g_wpa_l : g_wpt_l;

    const int tid = threadIdx.x;
    const int w = tid >> 6, l = tid & 63;
    const int rl = l & 15, g = l >> 4;
    const int lr0 = blockIdx.x * 64 + w * 16;
    const float* arow = A + (long)(lr0 + rl) * C_ + g * 8;

    f32x4 acc[8];
    #pragma unroll
    for (int i = 0; i < 8; ++i) acc[i] = (f32x4){0.f, 0.f, 0.f, 0.f};

    #pragma unroll
    for (int kp = 0; kp < 4; ++kp) {
        short8 ah, al;
        split8g(arow + kp * 32, ah, al);
        #pragma unroll
        for (int ct = 0; ct < 8; ++ct) {
            short8 bh  = *(const short8*)(Ph + (ct * 4 + kp) * 512 + l * 8);
            short8 blo = *(const short8*)(Pl + (ct * 4 + kp) * 512 + l * 8);
            acc[ct] = __builtin_amdgcn_mfma_f32_16x16x32_bf16(ah, bh, acc[ct], 0, 0, 0);
            acc[ct] = __builtin_amdgcn_mfma_f32_16x16x32_bf16(al, bh, acc[ct], 0, 0, 0);
            acc[ct] = __builtin_amdgcn_mfma_f32_16x16x32_bf16(ah, blo, acc[ct], 0, 0, 0);
        }
    }

    #pragma unroll
    for (int ct = 0; ct < 8; ++ct) {
        int cc = ct * 16 + rl;
        float bv = bias[cc];
        #pragma unroll
        for (int r = 0; r < 4; ++r)
            out[(long)(lr0 + g * 4 + r) * C_ + cc] = acc[ct][r] + bv;
    }
}

extern "C" void kernel_launch(void* const* d_in, const int* in_sizes, int n_in,
                              void* d_out, int out_size, void* d_ws, size_t ws_size,
                              hipStream_t stream) {
    const float* x       = (const float*)d_in[0];
    const int*   mask    = (const int*)d_in[1];
    const float* Wqkv_a  = (const float*)d_in[2];
    const float* Wproj_a = (const float*)d_in[3];
    const float* bproj_a = (const float*)d_in[4];
    const float* Wqkv_t  = (const float*)d_in[5];
    const float* Wproj_t = (const float*)d_in[6];
    const float* bproj_t = (const float*)d_in[7];
    float* out = (float*)d_out;
    float* yws = (float*)d_ws;   // pre-proj y, f32, 186368 x 128 = 95,420,416 B

    prep_all<<<64, 256, 0, stream>>>(Wqkv_a, Wqkv_t, Wproj_a, Wproj_t);

    const int NROWTILES = S_ * O_ * T_ / 64;   // 2912 blocks of 64 rows

    // ---- Pass 1: agent attention. batch (s,t), tokens = objects (N=64, NT=4).
    // attn: x -> yws (f32). proj: yws -> d_out as xa(s,t,o,c) (identity rows).
    {
        const size_t lds = 4 * 8192 + 4 * 64;
        attn_pass<O_, 4, 0><<<dim3(S_ * T_, 2), 256, lds, stream>>>(
            x, mask, yws,
            T_, (long)O_ * T_ * C_, (long)C_, (long)T_ * C_,
            1L, (long)T_);
        proj_gemm<0><<<NROWTILES, 256, 0, stream>>>(yws, bproj_a, out);
    }
    // ---- Pass 2: time attention. batch (s,o), tokens = timesteps (N=91, NT=6).
    // attn: reads xa from d_out, writes yws. proj: yws -> d_out final (s,o,t,c).
    {
        const size_t lds = 6 * 8192 + 6 * 64;
        attn_pass<T_, 6, 1><<<dim3(S_ * O_, 2), 256, lds, stream>>>(
            out, mask, yws,
            O_, (long)T_ * O_ * C_, (long)C_, (long)O_ * C_,
            (long)T_, 1L);
        proj_gemm<1><<<NROWTILES, 256, 0, stream>>>(yws, bproj_t, out);
    }
}